// Round 7
// baseline (29.542 us; speedup 1.0000x reference)
//
#include <hip/hip_runtime.h>
#include <stdint.h>

#define H 512
#define W 512
#define HW (H * W)
#define KT 81       // 9x9 taps per pixel
#define PAD 4
#define SEGW 64     // pixels per block (one row segment)
#define PW 520      // padded width/height
#define PPLANE (PW * PW)          // 270400 dwords per channel plane
#define PADTOT (3 * PPLANE)       // 811200 dwords

// 16B vector with 4B alignment: compiler emits unaligned global_load_dwordx4
// (HW-supported on gfx9+), or splits correctly if not.
typedef float f4u __attribute__((ext_vector_type(4), aligned(4)));

__device__ __forceinline__ int reflect_idx(int p) {
    // jnp.pad mode="reflect": pad (4) < 512, one fold suffices
    if (p < 0) p = -p;
    if (p >= H) p = 2 * H - 2 - p;
    return p;
}

// Kernel 1: build reflect-padded copy of x in workspace: xpad[3][520][520].
__global__ __launch_bounds__(256) void pad_kernel(
    const float* __restrict__ x, float* __restrict__ xpad)
{
    int idx = blockIdx.x * 256 + threadIdx.x;
    if (idx >= PADTOT) return;
    int c   = idx / PPLANE;
    int rem = idx - c * PPLANE;
    int r   = rem / PW;
    int col = rem - r * PW;
    xpad[idx] = x[(size_t)c * HW + reflect_idx(r - PAD) * W + reflect_idx(col - PAD)];
}

// Kernel 2: 192 threads = 3 waves; wave c computes channel c of a 64-px row
// segment. Weights staged coalesced->LDS, read back at dword stride 81
// (bank = (17*l + t) mod 32 = permutation -> conflict-free, pairs into
// ds_read2_b32). x read from the padded plane: per tap-row one unaligned
// dwordx4 + dwordx4 + dword = 3 VMEM ops for the 9-tap window (was 9).
__global__ __launch_bounds__(192) void svblur_kernel(
    const float* __restrict__ xpad,
    const float* __restrict__ kf,
    float* __restrict__ out)
{
    __shared__ float wlds[SEGW * KT];   // 20736 B -> 7 blocks/CU (21 waves)

    const int tid = (int)threadIdx.x;
    const int l   = tid & 63;           // lane = pixel in segment
    const int wv  = tid >> 6;           // wave id = channel (0..2)
    const int bid = (int)blockIdx.x;
    const int h   = bid >> 3;           // 512 rows
    const int w0  = (bid & 7) << 6;     // 8 segments of 64 px per row

    // ---- Stage weights: 5184 contiguous dwords = 1296 float4, 7 ops/wave.
    {
        const float4* ws = (const float4*)(kf + ((size_t)h * W + w0) * KT);
        float4* wd = (float4*)wlds;
#pragma unroll
        for (int it = 0; it < 7; ++it) {
            int idx = (wv * 7 + it) * 64 + l;
            if (idx < (SEGW * KT) / 4)
                wd[idx] = ws[idx];
        }
    }
    __syncthreads();

    // Output pixel (h, w0+l) reads xpad rows h..h+8, cols w0+l .. w0+l+8.
    const float* xbase = xpad + (size_t)wv * PPLANE + (size_t)h * PW + w0 + l;
    const float* wp = wlds + l * KT;

    float a0 = 0.f, a1 = 0.f, a2 = 0.f;
#pragma unroll
    for (int i = 0; i < 9; ++i) {
        const float* rp = xbase + i * PW;
        f4u A  = *(const f4u*)(rp);
        f4u Bv = *(const f4u*)(rp + 4);
        float Cv = rp[8];
        const float* wr = wp + i * 9;
        a0 = fmaf(A.x,  wr[0], a0);
        a1 = fmaf(A.y,  wr[1], a1);
        a2 = fmaf(A.z,  wr[2], a2);
        a0 = fmaf(A.w,  wr[3], a0);
        a1 = fmaf(Bv.x, wr[4], a1);
        a2 = fmaf(Bv.y, wr[5], a2);
        a0 = fmaf(Bv.z, wr[6], a0);
        a1 = fmaf(Bv.w, wr[7], a1);
        a2 = fmaf(Cv,   wr[8], a2);
    }

    out[(size_t)wv * HW + h * W + w0 + l] = a0 + a1 + a2;
}

extern "C" void kernel_launch(void* const* d_in, const int* in_sizes, int n_in,
                              void* d_out, int out_size, void* d_ws, size_t ws_size,
                              hipStream_t stream) {
    const float* x  = (const float*)d_in[0];
    const float* kf = (const float*)d_in[1];
    float* out  = (float*)d_out;
    float* xpad = (float*)d_ws;   // 3.25 MB of workspace

    pad_kernel<<<(PADTOT + 255) / 256, 256, 0, stream>>>(x, xpad);
    svblur_kernel<<<H * (W / SEGW), 192, 0, stream>>>(xpad, kf, out);
}